// Round 9
// baseline (280.689 us; speedup 1.0000x reference)
//
#include <hip/hip_runtime.h>
#include <hip/hip_bf16.h>

#define G     32
#define NPG   512
#define EPG   8192
#define GN    16384        // G*NPG
#define ETOT  (G*EPG)      // 262144
#define CIN   64
#define H     128
#define NB    4
#define S     4096         // T*NPG
#define HEADS 4
#define HD    32
#define QKV   384

typedef __attribute__((ext_vector_type(8))) short short8;
typedef __attribute__((ext_vector_type(4))) float floatx4;

__device__ __forceinline__ float bf16_to_f32(unsigned short u) {
    unsigned int x = ((unsigned int)u) << 16;
    return __uint_as_float(x);
}
__device__ __forceinline__ unsigned short f32_to_bf16(float f) {
    __hip_bfloat16 h = (__hip_bfloat16)f;
    return *(unsigned short*)&h;
}
__device__ __forceinline__ float ldf(const void* p, long i, int f32) {
    return f32 ? ((const float*)p)[i] : bf16_to_f32(((const unsigned short*)p)[i]);
}

// fast exp2: v_exp_f32 is ~26 cy issue-blocking per wave64 (measured: 235 cy
// VALU-busy per attn tile-chunk = 8*E + ~24 glue).  Full-rate replacement:
// n=rne(x), f=x-n in [-.5,.5], deg-3 poly (rel err ~2e-4 << bf16 eps), ldexp.
// 7 ops * 2 cy = ~14 cy.
__device__ __forceinline__ float fexp2(float x) {
    float n = __builtin_rintf(x);
    float f = x - n;
    int ni = (int)n;
    float p = __builtin_fmaf(__builtin_fmaf(__builtin_fmaf(
        0.0576583f, f, 0.2402265f), f, 0.6931472f), f, 1.0f);
    float r;
    asm("v_ldexp_f32 %0, %1, %2" : "=v"(r) : "v"(p), "v"(ni));
    return r;
}

// ---------- runtime dtype detection ----------
__global__ void detect_kernel(const unsigned short* __restrict__ xraw,
                              const int* __restrict__ eiraw, int* __restrict__ flags) {
    __shared__ float smax[256];
    __shared__ int   sor[256];
    int t = threadIdx.x;
    float m = 0.f;
    for (int i = t; i < 4096; i += 256)
        m = fmaxf(m, fabsf(bf16_to_f32(xraw[i])));
    int orv = 0;
    for (int i = t; i < 2048; i += 256)
        orv |= eiraw[2 * i + 1];
    smax[t] = m; sor[t] = orv;
    __syncthreads();
    for (int off = 128; off > 0; off >>= 1) {
        if (t < off) {
            smax[t] = fmaxf(smax[t], smax[t + off]);
            sor[t] |= sor[t + off];
        }
        __syncthreads();
    }
    if (t == 0) {
        flags[0] = (smax[0] > 1000.f) ? 1 : 0;
        flags[1] = (sor[0] == 0) ? 1 : 0;
    }
}

// ---------- CSR build: count + scan + dinv + fill, one block per graph ----------
__global__ __launch_bounds__(NPG) void csr_kernel(const int* __restrict__ ei,
        const int* __restrict__ flags, int* __restrict__ cnt_g,
        int* __restrict__ row_start_g, float* __restrict__ dinv_g,
        int* __restrict__ csr_src) {
    __shared__ int cs[NPG], ctmp[NPG], fpos[NPG];
    int g = blockIdx.x, t = threadIdx.x;
    int sh = flags[1];
    cs[t] = 0;
    __syncthreads();
    const size_t sbase = ((size_t)(g * 2 + 0) * EPG) << sh;
    const size_t dbase = ((size_t)(g * 2 + 1) * EPG) << sh;
    for (int e = t; e < EPG; e += NPG)
        atomicAdd(&cs[ei[dbase + ((size_t)e << sh)]], 1);
    __syncthreads();
    int c = cs[t];
    ctmp[t] = c;
    __syncthreads();
    for (int off = 1; off < NPG; off <<= 1) {
        int v = (t >= off) ? ctmp[t - off] : 0;
        __syncthreads();
        ctmp[t] += v;
        __syncthreads();
    }
    int rs = g * EPG + ctmp[t] - c;            // exclusive prefix
    fpos[t] = rs;
    cnt_g[g * NPG + t] = c;
    row_start_g[g * NPG + t] = rs;
    dinv_g[g * NPG + t] = 1.0f / sqrtf((float)c + 1.0f);
    __syncthreads();
    for (int e = t; e < EPG; e += NPG) {
        int s = ei[sbase + ((size_t)e << sh)];
        int d = ei[dbase + ((size_t)e << sh)];
        int pos = atomicAdd(&fpos[d], 1);
        csr_src[pos] = g * NPG + s;
    }
}

// ---------- fused conversion: everything -> bf16 (weights pre-transposed) ----------
// x additionally scaled by dinv[node] (reassociated GCN layer 1).
#define XN   (GN*CIN)          // x:      [0,      XN)
#define E1   (XN + H*CIN)      // W1T
#define E2   (E1 + H*H)        // W2T
#define E3   (E2 + QKV*H)      // Wqkv
#define E4   (E3 + H*H)        // Wo
#define E5   (E4 + H)          // b1
#define E6   (E5 + H)          // b2
#define E7   (E6 + QKV)        // bqkv
#define CTOT (E7 + H)          // bo
__global__ void conv_all_kernel(const void* x_raw, const void* W1_raw, const void* b1_raw,
                                const void* W2_raw, const void* b2_raw, const void* Wq_raw,
                                const void* bq_raw, const void* Wo_raw, const void* bo_raw,
                                unsigned short* __restrict__ xb,
                                unsigned short* __restrict__ W1T,
                                unsigned short* __restrict__ W2T,
                                unsigned short* __restrict__ Wqb,
                                unsigned short* __restrict__ Wob,
                                float* __restrict__ b1f, float* __restrict__ b2f,
                                float* __restrict__ bqf, float* __restrict__ bof,
                                const float* __restrict__ dinv,
                                const int* __restrict__ flags) {
    int i = blockIdx.x * blockDim.x + threadIdx.x;
    if (i >= CTOT) return;
    int f32 = flags[0];
    if (i < XN) {              // x scaled by dinv of its node (CIN=64 -> node = i>>6)
        xb[i] = f32_to_bf16(ldf(x_raw, i, f32) * dinv[i >> 6]);
    } else if (i < E1) {       // W1T[c][r] = W1[r][c], [H out][CIN in]
        int j = i - XN, c = j / CIN, r = j - c * CIN;
        W1T[j] = f32_to_bf16(ldf(W1_raw, (long)r * H + c, f32));
    } else if (i < E2) {       // W2T[c][r] = W2[r][c]
        int j = i - E1, c = j >> 7, r = j & 127;
        W2T[j] = f32_to_bf16(ldf(W2_raw, (long)r * H + c, f32));
    } else if (i < E3) {       // in_proj_w already [out][in]
        int j = i - E2;
        Wqb[j] = f32_to_bf16(ldf(Wq_raw, j, f32));
    } else if (i < E4) {
        int j = i - E3;
        Wob[j] = f32_to_bf16(ldf(Wo_raw, j, f32));
    } else if (i < E5) { b1f[i - E4] = ldf(b1_raw, i - E4, f32); }
    else if (i < E6) { b2f[i - E5] = ldf(b2_raw, i - E5, f32); }
    else if (i < E7) { bqf[i - E6] = ldf(bq_raw, i - E6, f32); }
    else             { bof[i - E7] = ldf(bo_raw, i - E7, f32); }
}

// ---------- layer-1 aggregation, vectorized gather: 8 lanes x short8 per row ----
__global__ void agg64_kernel(const unsigned short* __restrict__ xb,
                             const int* __restrict__ row_start, const int* __restrict__ cnt,
                             const int* __restrict__ csr_src, const float* __restrict__ dinv,
                             unsigned short* __restrict__ z) {
    int i = blockIdx.x;
    int t = threadIdx.x;                    // 64
    int sl = t & 7, gp = t >> 3;            // slice: 8 ch; group: 8 edges in flight
    float a[8] = {0.f, 0.f, 0.f, 0.f, 0.f, 0.f, 0.f, 0.f};
    int rs = row_start[i], n = cnt[i];
    for (int p = gp; p < n; p += 8) {
        int s = csr_src[rs + p];            // broadcast within 8-lane slice group
        short8 v = *(const short8*)&xb[(size_t)s * CIN + sl * 8];
#pragma unroll
        for (int j = 0; j < 8; j++)
            a[j] += bf16_to_f32((unsigned short)v[j]);
    }
#pragma unroll
    for (int off = 8; off < 64; off <<= 1)
#pragma unroll
        for (int j = 0; j < 8; j++)
            a[j] += __shfl_xor(a[j], off);
    if (gp == 0) {                          // lanes 0..7 finalize + store 16B each
        float dv = dinv[i];
        short8 selfv = *(const short8*)&xb[(size_t)i * CIN + sl * 8];
        short8 o;
#pragma unroll
        for (int j = 0; j < 8; j++)
            o[j] = (short)f32_to_bf16((a[j] + bf16_to_f32((unsigned short)selfv[j])) * dv);
        *(short8*)&z[(size_t)i * CIN + sl * 8] = o;
    }
}

// ---------- fused GCN GEMMs: h = z*W1+b1 (K=64) -> LDS -> y = (h*W2)*dinv (K=128)
#define HPAD 136
__global__ __launch_bounds__(256) void gcn12_kernel(
        const unsigned short* __restrict__ Z, const unsigned short* __restrict__ W1T,
        const float* __restrict__ b1, const unsigned short* __restrict__ W2T,
        const float* __restrict__ dinv, unsigned short* __restrict__ Y) {
    __shared__ unsigned short hl[64][HPAD];
    int tid = threadIdx.x, wave = tid >> 6, lane = tid & 63, m = lane & 15, quad = lane >> 4;
    int row0 = blockIdx.x * 64 + wave * 16;
    int lrow0 = wave * 16;
    floatx4 acc[8] = {};
    for (int kc = 0; kc < CIN; kc += 32) {
        short8 af = *(const short8*)&Z[(size_t)(row0 + m) * CIN + kc + quad * 8];
#pragma unroll
        for (int t = 0; t < 8; t++) {
            short8 bf = *(const short8*)&W1T[(size_t)(t * 16 + m) * CIN + kc + quad * 8];
            acc[t] = __builtin_amdgcn_mfma_f32_16x16x32_bf16(af, bf, acc[t], 0, 0, 0);
        }
    }
#pragma unroll
    for (int t = 0; t < 8; t++) {
        int col = t * 16 + m;
        float bj = b1[col];
#pragma unroll
        for (int r = 0; r < 4; r++)
            hl[lrow0 + quad * 4 + r][col] = f32_to_bf16(acc[t][r] + bj);
    }
    asm volatile("s_waitcnt lgkmcnt(0)" ::: "memory");
    floatx4 acc2[8] = {};
    for (int kc = 0; kc < H; kc += 32) {
        short8 af = *(const short8*)&hl[lrow0 + m][kc + quad * 8];
#pragma unroll
        for (int t = 0; t < 8; t++) {
            short8 bf = *(const short8*)&W2T[(size_t)(t * 16 + m) * H + kc + quad * 8];
            acc2[t] = __builtin_amdgcn_mfma_f32_16x16x32_bf16(af, bf, acc2[t], 0, 0, 0);
        }
    }
    int rbase = row0 + quad * 4;
    float4 dv4 = *(const float4*)&dinv[rbase];
    float dv[4] = {dv4.x, dv4.y, dv4.z, dv4.w};
#pragma unroll
    for (int t = 0; t < 8; t++) {
        int col = t * 16 + m;
#pragma unroll
        for (int r = 0; r < 4; r++)
            Y[(size_t)(rbase + r) * H + col] = f32_to_bf16(acc2[t][r] * dv[r]);
    }
}

// ---------- layer-2 aggregation, vectorized gather: 16 lanes x short8 per row ----
__global__ void agg_kernel(const unsigned short* __restrict__ y,
                           const int* __restrict__ row_start, const int* __restrict__ cnt,
                           const int* __restrict__ csr_src, const float* __restrict__ dinv,
                           const float* __restrict__ bias, unsigned short* __restrict__ hout) {
    __shared__ float sred[16][8];
    int i = blockIdx.x;
    int t = threadIdx.x;                    // 128
    int sl = t & 15, gp = t >> 4;           // slice: 8 ch; groups 0-3 wave0, 4-7 wave1
    float a[8] = {0.f, 0.f, 0.f, 0.f, 0.f, 0.f, 0.f, 0.f};
    int rs = row_start[i], n = cnt[i];
    for (int p = gp; p < n; p += 8) {
        int s = csr_src[rs + p];            // broadcast within 16-lane slice group
        short8 v = *(const short8*)&y[(size_t)s * H + sl * 8];
#pragma unroll
        for (int j = 0; j < 8; j++)
            a[j] += bf16_to_f32((unsigned short)v[j]);
    }
#pragma unroll
    for (int off = 16; off < 64; off <<= 1)
#pragma unroll
        for (int j = 0; j < 8; j++)
            a[j] += __shfl_xor(a[j], off);
    if (t >= 64 && t < 80) {                // wave1 lanes 0..15: publish partials
#pragma unroll
        for (int j = 0; j < 8; j++) sred[sl][j] = a[j];
    }
    __syncthreads();
    if (t < 16) {                           // wave0 lanes 0..15 finalize + store
        float dv = dinv[i];
        short8 selfv = *(const short8*)&y[(size_t)i * H + sl * 8];
        short8 o;
#pragma unroll
        for (int j = 0; j < 8; j++) {
            float x = (a[j] + sred[sl][j] + bf16_to_f32((unsigned short)selfv[j])) * dv
                      + bias[sl * 8 + j];
            o[j] = (short)f32_to_bf16(x);
        }
        *(short8*)&hout[(size_t)i * H + sl * 8] = o;
    }
}

// ---------- QKV GEMM (N=384) with blocked epilogue ----------
__global__ __launch_bounds__(256) void mmqkv_kernel(const unsigned short* __restrict__ A,
        const unsigned short* __restrict__ B, const float* __restrict__ bias,
        unsigned short* __restrict__ Qx, unsigned short* __restrict__ Kx,
        unsigned short* __restrict__ Vtx) {
    __shared__ unsigned short vbuf[4][2][16][20];   // [wave][parity][hd][s(+pad)]
    int tid = threadIdx.x, wave = tid >> 6, lane = tid & 63, m = lane & 15, quad = lane >> 4;
    int row0 = blockIdx.x * 64 + wave * 16;
    floatx4 acc[24] = {};
    for (int kc = 0; kc < H; kc += 32) {
        short8 af = *(const short8*)&A[(size_t)(row0 + m) * H + kc + quad * 8];
#pragma unroll
        for (int t = 0; t < 24; t++) {
            short8 bf = *(const short8*)&B[(size_t)(t * 16 + m) * H + kc + quad * 8];
            acc[t] = __builtin_amdgcn_mfma_f32_16x16x32_bf16(af, bf, acc[t], 0, 0, 0);
        }
    }
    int rbase = row0 + quad * 4;                    // rows rbase..rbase+3, same batch
    int b = rbase >> 12, s0 = rbase & (S - 1);
    int s0t = row0 & (S - 1);                       // wave-tile base s (16 rows)
    int hdl = lane >> 2, sg = lane & 3;             // transposed-read mapping
#pragma unroll
    for (int t = 0; t < 24; t++) {
        int j = t * 16 + m;                         // 0..383
        float bj = bias[j];
        if (t < 8) {                                // Q (pre-scaled by log2e/sqrt(hd))
            int head = j >> 5, hd = j & 31;
            int bh = b * HEADS + head;
#pragma unroll
            for (int r = 0; r < 4; r++)
                Qx[((size_t)bh * S + s0 + r) * HD + hd] =
                    f32_to_bf16((acc[t][r] + bj) *
                                (0.17677669529663687f * 1.4426950408889634f));
        } else if (t < 16) {                        // K
            int jj = j & 127, head = jj >> 5, hd = jj & 31;
            int bh = b * HEADS + head;
#pragma unroll
            for (int r = 0; r < 4; r++)
                Kx[((size_t)bh * S + s0 + r) * HD + hd] = f32_to_bf16(acc[t][r] + bj);
        } else {                                    // V transposed via LDS
            int t2 = t - 16;                        // 0..7
            int head = t2 >> 1, hdb = (t2 & 1) * 16;
            int bh = b * HEADS + head;
            float v0 = acc[t][0] + bj, v1 = acc[t][1] + bj;
            float v2 = acc[t][2] + bj, v3 = acc[t][3] + bj;
            unsigned int d0, d1;
            asm("v_cvt_pk_bf16_f32 %0, %1, %2" : "=v"(d0) : "v"(v0), "v"(v1));
            asm("v_cvt_pk_bf16_f32 %0, %1, %2" : "=v"(d1) : "v"(v2), "v"(v3));
            uint2 wv; wv.x = d0; wv.y = d1;
            *(uint2*)&vbuf[wave][t2 & 1][m][quad * 4] = wv;
            asm volatile("s_waitcnt lgkmcnt(0)" ::: "memory");
            uint2 rv = *(const uint2*)&vbuf[wave][t2 & 1][hdl][sg * 4];
            *(uint2*)&Vtx[((size_t)bh * HD + hdb + hdl) * S + s0t + sg * 4] = rv;
        }
    }
}

// ---------- MFMA flash attention v8: v7 + fast-exp2 (full-rate poly replaces
// ~26cy v_exp_f32) + wrap-free pointer-increment prefetch (last-iter prefetch
// lands in the pad region after Vtx; loaded, never used).
// grid 256 (1 block/CU, 1 wave/SIMD), block 256, LDS 0.
__global__ __launch_bounds__(256) void attn8_kernel(
        const unsigned short* __restrict__ Qx, const unsigned short* __restrict__ Kx,
        const unsigned short* __restrict__ Vtx, unsigned short* __restrict__ Ob) {
    int tid = threadIdx.x, wave = tid >> 6, lane = tid & 63;
    int m = lane & 15, quad = lane >> 4;

    int n = blockIdx.x;                       // 0..255, XCD ~ n%8
    int id = (n & 7) * 32 + (n >> 3);         // XCD x owns ids [32x,32x+32) -> bh {2x,2x+1}
    int tile = id & 15, bh = id >> 4;

    const unsigned short* Qb  = Qx  + (size_t)bh * S * HD;
    const unsigned short* Kb  = Kx  + (size_t)bh * S * HD;
    const unsigned short* Vtb = Vtx + (size_t)bh * HD * S;

    int q0 = tile * 256 + wave * 64;
    short8 q[4];
#pragma unroll
    for (int t = 0; t < 4; t++)
        q[t] = *(const short8*)&Qb[(size_t)(q0 + t * 16 + m) * HD + quad * 8];

    floatx4 o0[4] = {}, o1[4] = {}, l[4] = {};

    short8 ones = {16256, 16256, 16256, 16256, 16256, 16256, 16256, 16256}; // bf16 1.0
    union PW { unsigned int u[4]; short8 s8; };

    // chunk 0 K/V + wrap-free prefetch pointers
    const unsigned short* kp0 = Kb + (size_t)m * HD + quad * 8;
    const unsigned short* kp1 = Kb + (size_t)(m + 16) * HD + quad * 8;
    const unsigned short* vq0 = Vtb + (size_t)m * S + quad * 8;
    const unsigned short* vq1 = Vtb + (size_t)(m + 16) * S + quad * 8;
    short8 kf0 = *(const short8*)kp0;
    short8 kf1 = *(const short8*)kp1;
    short8 vc0 = *(const short8*)vq0;
    short8 vc1 = *(const short8*)vq1;

    for (int i = 0; i < S / 32; i++) {
        floatx4 z = {};
        // swapped QK^T for all 4 q-tiles (lane(m,quad): P^T[k=quad*4+r][q=m])
        floatx4 t0[4], t1[4];
#pragma unroll
        for (int t = 0; t < 4; t++) {
            t0[t] = __builtin_amdgcn_mfma_f32_16x16x32_bf16(kf0, q[t], z, 0, 0, 0);
            t1[t] = __builtin_amdgcn_mfma_f32_16x16x32_bf16(kf1, q[t], z, 0, 0, 0);
        }
        // K prefetch chunk i+1 (pointer increment; last iter reads pad)
        kp0 += 32 * HD; kp1 += 32 * HD;
        kf0 = *(const short8*)kp0;
        kf1 = *(const short8*)kp1;

        // fast exp2 -> pack bf16 -> in-register transpose, per tile
        PW pw[4];
#pragma unroll
        for (int t = 0; t < 4; t++) {
            float e0 = fexp2(t0[t][0]);
            float e1 = fexp2(t0[t][1]);
            float e2 = fexp2(t0[t][2]);
            float e3 = fexp2(t0[t][3]);
            float e4 = fexp2(t1[t][0]);
            float e5 = fexp2(t1[t][1]);
            float e6 = fexp2(t1[t][2]);
            float e7 = fexp2(t1[t][3]);
            unsigned int w0, w1, w2, w3;
            asm("v_cvt_pk_bf16_f32 %0, %1, %2" : "=v"(w0) : "v"(e0), "v"(e1));
            asm("v_cvt_pk_bf16_f32 %0, %1, %2" : "=v"(w1) : "v"(e2), "v"(e3));
            asm("v_cvt_pk_bf16_f32 %0, %1, %2" : "=v"(w2) : "v"(e4), "v"(e5));
            asm("v_cvt_pk_bf16_f32 %0, %1, %2" : "=v"(w3) : "v"(e6), "v"(e7));
            asm("v_permlane32_swap_b32 %0, %1" : "+v"(w0), "+v"(w2));
            asm("v_permlane32_swap_b32 %0, %1" : "+v"(w1), "+v"(w3));
            asm("v_permlane16_swap_b32 %0, %1" : "+v"(w0), "+v"(w2));
            asm("v_permlane16_swap_b32 %0, %1" : "+v"(w1), "+v"(w3));
            pw[t].u[0] = w0; pw[t].u[1] = w1; pw[t].u[2] = w2; pw[t].u[3] = w3;
        }

        // PV + row-sum l (MFMA pipe), then V prefetch chunk i+1
#pragma unroll
        for (int t = 0; t < 4; t++) {
            o0[t] = __builtin_amdgcn_mfma_f32_16x16x32_bf16(pw[t].s8, vc0, o0[t], 0, 0, 0);
            o1[t] = __builtin_amdgcn_mfma_f32_16x16x32_bf16(pw[t].s8, vc1, o1[t], 0, 0, 0);
            l[t]  = __builtin_amdgcn_mfma_f32_16x16x32_bf16(pw[t].s8, ones, l[t], 0, 0, 0);
        }
        vq0 += 32; vq1 += 32;
        vc0 = *(const short8*)vq0;
        vc1 = *(const short8*)vq1;
    }

    // epilogue: l is row-aligned with O (row = quad*4+r), no shuffles
    int batch = bh >> 2, head = bh & 3;
    int col = head * HD + m;
#pragma unroll
    for (int t = 0; t < 4; t++) {
        int grow = batch * S + q0 + t * 16 + quad * 4;
#pragma unroll
        for (int r = 0; r < 4; r++) {
            float inv = 1.f / l[t][r];
            Ob[(size_t)(grow + r) * H + col]      = f32_to_bf16(o0[t][r] * inv);
            Ob[(size_t)(grow + r) * H + col + 16] = f32_to_bf16(o1[t][r] * inv);
        }
    }
}

// ---------- output projection GEMM (N=128) + bias, dual-dtype store ----------
__global__ __launch_bounds__(256) void mmout_kernel(const unsigned short* __restrict__ A,
        const unsigned short* __restrict__ B, const float* __restrict__ bias,
        void* __restrict__ out, const int* __restrict__ flags) {
    int tid = threadIdx.x, wave = tid >> 6, lane = tid & 63, m = lane & 15, quad = lane >> 4;
    int row0 = blockIdx.x * 64 + wave * 16;
    floatx4 acc[8] = {};
    for (int kc = 0; kc < H; kc += 32) {
        short8 af = *(const short8*)&A[(size_t)(row0 + m) * H + kc + quad * 8];
#pragma unroll
        for (int t = 0; t < 8; t++) {
            short8 bf = *(const short8*)&B[(size_t)(t * 16 + m) * H + kc + quad * 8];
            acc[t] = __builtin_amdgcn_mfma_f32_16x16x32_bf16(af, bf, acc[t], 0, 0, 0);
        }
    }
    int rbase = row0 + quad * 4;
    int f32o = flags[0];
#pragma unroll
    for (int t = 0; t < 8; t++) {
        int col = t * 16 + m;
        float bj = bias[col];
#pragma unroll
        for (int r = 0; r < 4; r++) {
            float v = acc[t][r] + bj;
            if (f32o) ((float*)out)[(size_t)(rbase + r) * H + col] = v;
            else ((unsigned short*)out)[(size_t)(rbase + r) * H + col] = f32_to_bf16(v);
        }
    }
}

extern "C" void kernel_launch(void* const* d_in, const int* in_sizes, int n_in,
                              void* d_out, int out_size, void* d_ws, size_t ws_size,
                              hipStream_t stream) {
    const void* x_raw    = d_in[0];
    const int*  ei_raw   = (const int*)d_in[1];
    const void* W1_raw   = d_in[2];
    const void* b1_raw   = d_in[3];
    const void* W2_raw   = d_in[4];
    const void* b2_raw   = d_in[5];
    const void* Wq_raw   = d_in[6];
    const void* bq_raw   = d_in[7];
    const void* Wo_raw   = d_in[8];
    const void* bo_raw   = d_in[9];

    char* ws = (char*)d_ws;
    size_t o = 0;
    auto alloc = [&](size_t bytes) { void* p = ws + o; o += (bytes + 1023) & ~1023ull; return p; };

    int*   flags     = (int*)  alloc(1024);
    int*   cnt       = (int*)  alloc((size_t)GN * 4);
    int*   row_start = (int*)  alloc((size_t)GN * 4);
    float* dinv      = (float*)alloc((size_t)GN * 4);
    int*   csr_src   = (int*)  alloc((size_t)ETOT * 4);
    unsigned short* xb   = (unsigned short*)alloc((size_t)GN * CIN * 2);
    unsigned short* zb   = (unsigned short*)alloc((size_t)GN * CIN * 2);
    unsigned short* W1T  = (unsigned short*)alloc((size_t)H * CIN * 2);
    unsigned short* W2T  = (unsigned short*)alloc((size_t)H * H * 2);
    unsigned short* Wqb  = (unsigned short*)alloc((size_t)QKV * H * 2);
    unsigned short* Wob  = (unsigned short*)alloc((size_t)H * H * 2);
    float* b1f = (float*)alloc(H * 4);
    float* b2f = (float*)alloc(H * 4);
    float* bqf = (float*)alloc(QKV * 4);
    float* bof = (float*)alloc(H * 4);
    unsigned short* y_bf = (unsigned short*)alloc((size_t)GN * H * 2);
    unsigned short* h_bf = (unsigned short*)alloc((size_t)GN * H * 2);
    unsigned short* Qx   = (unsigned short*)alloc((size_t)16 * S * HD * 2);
    unsigned short* Kx   = (unsigned short*)alloc((size_t)16 * S * HD * 2);
    unsigned short* Vtx  = (unsigned short*)alloc((size_t)16 * S * HD * 2);
    (void)alloc(32768);            // pad: wrap-free attn prefetch overruns land here
    unsigned short* Obf  = y_bf;   // y dead after agg

    detect_kernel<<<1, 256, 0, stream>>>((const unsigned short*)x_raw, ei_raw, flags);

    // CSR build: count+scan+dinv+fill in one dispatch (LDS atomics)
    csr_kernel<<<G, NPG, 0, stream>>>(ei_raw, flags, cnt, row_start, dinv, csr_src);

    // conversion (x pre-scaled by dinv for the reassociated layer 1)
    conv_all_kernel<<<(CTOT + 255) / 256, 256, 0, stream>>>(
        x_raw, W1_raw, b1_raw, W2_raw, b2_raw, Wq_raw, bq_raw, Wo_raw, bo_raw,
        xb, W1T, W2T, Wqb, Wob, b1f, b2f, bqf, bof, dinv, flags);

    // GCN layer 1 aggregate (vectorized), then fused GEMM1+GEMM2 (h in LDS)
    agg64_kernel<<<GN, 64, 0, stream>>>(xb, row_start, cnt, csr_src, dinv, zb);
    gcn12_kernel<<<GN / 64, 256, 0, stream>>>(zb, W1T, b1f, W2T, dinv, y_bf);
    // GCN layer 2 aggregate (vectorized) + bias
    agg_kernel<<<GN, 128, 0, stream>>>(y_bf, row_start, cnt, csr_src, dinv, b2f, h_bf);

    // attention
    mmqkv_kernel<<<GN / 64, 256, 0, stream>>>(h_bf, Wqb, bqf, Qx, Kx, Vtx);
    attn8_kernel<<<dim3(256), 256, 0, stream>>>(Qx, Kx, Vtx, Obf);
    mmout_kernel<<<GN / 64, 256, 0, stream>>>(Obf, Wob, bof, d_out, flags);
}

// Round 10
// 244.817 us; speedup vs baseline: 1.1465x; 1.1465x over previous
//
#include <hip/hip_runtime.h>
#include <hip/hip_bf16.h>

#define G     32
#define NPG   512
#define EPG   8192
#define GN    16384        // G*NPG
#define ETOT  (G*EPG)      // 262144
#define CIN   64
#define H     128
#define NB    4
#define S     4096         // T*NPG
#define HEADS 4
#define HD    32
#define QKV   384

typedef __attribute__((ext_vector_type(8))) short short8;
typedef __attribute__((ext_vector_type(4))) float floatx4;

__device__ __forceinline__ float bf16_to_f32(unsigned short u) {
    unsigned int x = ((unsigned int)u) << 16;
    return __uint_as_float(x);
}
__device__ __forceinline__ unsigned short f32_to_bf16(float f) {
    __hip_bfloat16 h = (__hip_bfloat16)f;
    return *(unsigned short*)&h;
}
__device__ __forceinline__ float ldf(const void* p, long i, int f32) {
    return f32 ? ((const float*)p)[i] : bf16_to_f32(((const unsigned short*)p)[i]);
}

// ---------- runtime dtype detection ----------
__global__ void detect_kernel(const unsigned short* __restrict__ xraw,
                              const int* __restrict__ eiraw, int* __restrict__ flags) {
    __shared__ float smax[256];
    __shared__ int   sor[256];
    int t = threadIdx.x;
    float m = 0.f;
    for (int i = t; i < 4096; i += 256)
        m = fmaxf(m, fabsf(bf16_to_f32(xraw[i])));
    int orv = 0;
    for (int i = t; i < 2048; i += 256)
        orv |= eiraw[2 * i + 1];
    smax[t] = m; sor[t] = orv;
    __syncthreads();
    for (int off = 128; off > 0; off >>= 1) {
        if (t < off) {
            smax[t] = fmaxf(smax[t], smax[t + off]);
            sor[t] |= sor[t + off];
        }
        __syncthreads();
    }
    if (t == 0) {
        flags[0] = (smax[0] > 1000.f) ? 1 : 0;
        flags[1] = (sor[0] == 0) ? 1 : 0;
    }
}

// ---------- CSR build: count + scan + dinv + fill, one block per graph ----------
__global__ __launch_bounds__(NPG) void csr_kernel(const int* __restrict__ ei,
        const int* __restrict__ flags, int* __restrict__ cnt_g,
        int* __restrict__ row_start_g, float* __restrict__ dinv_g,
        int* __restrict__ csr_src) {
    __shared__ int cs[NPG], ctmp[NPG], fpos[NPG];
    int g = blockIdx.x, t = threadIdx.x;
    int sh = flags[1];
    cs[t] = 0;
    __syncthreads();
    const size_t sbase = ((size_t)(g * 2 + 0) * EPG) << sh;
    const size_t dbase = ((size_t)(g * 2 + 1) * EPG) << sh;
    for (int e = t; e < EPG; e += NPG)
        atomicAdd(&cs[ei[dbase + ((size_t)e << sh)]], 1);
    __syncthreads();
    int c = cs[t];
    ctmp[t] = c;
    __syncthreads();
    for (int off = 1; off < NPG; off <<= 1) {
        int v = (t >= off) ? ctmp[t - off] : 0;
        __syncthreads();
        ctmp[t] += v;
        __syncthreads();
    }
    int rs = g * EPG + ctmp[t] - c;            // exclusive prefix
    fpos[t] = rs;
    cnt_g[g * NPG + t] = c;
    row_start_g[g * NPG + t] = rs;
    dinv_g[g * NPG + t] = 1.0f / sqrtf((float)c + 1.0f);
    __syncthreads();
    for (int e = t; e < EPG; e += NPG) {
        int s = ei[sbase + ((size_t)e << sh)];
        int d = ei[dbase + ((size_t)e << sh)];
        int pos = atomicAdd(&fpos[d], 1);
        csr_src[pos] = g * NPG + s;
    }
}

// ---------- fused conversion: everything -> bf16 (weights pre-transposed) ----------
// x additionally scaled by dinv[node] (reassociated GCN layer 1).
#define XN   (GN*CIN)          // x:      [0,      XN)
#define E1   (XN + H*CIN)      // W1T
#define E2   (E1 + H*H)        // W2T
#define E3   (E2 + QKV*H)      // Wqkv
#define E4   (E3 + H*H)        // Wo
#define E5   (E4 + H)          // b1
#define E6   (E5 + H)          // b2
#define E7   (E6 + QKV)        // bqkv
#define CTOT (E7 + H)          // bo
__global__ void conv_all_kernel(const void* x_raw, const void* W1_raw, const void* b1_raw,
                                const void* W2_raw, const void* b2_raw, const void* Wq_raw,
                                const void* bq_raw, const void* Wo_raw, const void* bo_raw,
                                unsigned short* __restrict__ xb,
                                unsigned short* __restrict__ W1T,
                                unsigned short* __restrict__ W2T,
                                unsigned short* __restrict__ Wqb,
                                unsigned short* __restrict__ Wob,
                                float* __restrict__ b1f, float* __restrict__ b2f,
                                float* __restrict__ bqf, float* __restrict__ bof,
                                const float* __restrict__ dinv,
                                const int* __restrict__ flags) {
    int i = blockIdx.x * blockDim.x + threadIdx.x;
    if (i >= CTOT) return;
    int f32 = flags[0];
    if (i < XN) {              // x scaled by dinv of its node (CIN=64 -> node = i>>6)
        xb[i] = f32_to_bf16(ldf(x_raw, i, f32) * dinv[i >> 6]);
    } else if (i < E1) {       // W1T[c][r] = W1[r][c], [H out][CIN in]
        int j = i - XN, c = j / CIN, r = j - c * CIN;
        W1T[j] = f32_to_bf16(ldf(W1_raw, (long)r * H + c, f32));
    } else if (i < E2) {       // W2T[c][r] = W2[r][c]
        int j = i - E1, c = j >> 7, r = j & 127;
        W2T[j] = f32_to_bf16(ldf(W2_raw, (long)r * H + c, f32));
    } else if (i < E3) {       // in_proj_w already [out][in]
        int j = i - E2;
        Wqb[j] = f32_to_bf16(ldf(Wq_raw, j, f32));
    } else if (i < E4) {
        int j = i - E3;
        Wob[j] = f32_to_bf16(ldf(Wo_raw, j, f32));
    } else if (i < E5) { b1f[i - E4] = ldf(b1_raw, i - E4, f32); }
    else if (i < E6) { b2f[i - E5] = ldf(b2_raw, i - E5, f32); }
    else if (i < E7) { bqf[i - E6] = ldf(bq_raw, i - E6, f32); }
    else             { bof[i - E7] = ldf(bo_raw, i - E7, f32); }
}

// ---------- layer-1 aggregation, vectorized gather: 8 lanes x short8 per row ----
__global__ void agg64_kernel(const unsigned short* __restrict__ xb,
                             const int* __restrict__ row_start, const int* __restrict__ cnt,
                             const int* __restrict__ csr_src, const float* __restrict__ dinv,
                             unsigned short* __restrict__ z) {
    int i = blockIdx.x;
    int t = threadIdx.x;                    // 64
    int sl = t & 7, gp = t >> 3;            // slice: 8 ch; group: 8 edges in flight
    float a[8] = {0.f, 0.f, 0.f, 0.f, 0.f, 0.f, 0.f, 0.f};
    int rs = row_start[i], n = cnt[i];
    for (int p = gp; p < n; p += 8) {
        int s = csr_src[rs + p];            // broadcast within 8-lane slice group
        short8 v = *(const short8*)&xb[(size_t)s * CIN + sl * 8];
#pragma unroll
        for (int j = 0; j < 8; j++)
            a[j] += bf16_to_f32((unsigned short)v[j]);
    }
#pragma unroll
    for (int off = 8; off < 64; off <<= 1)
#pragma unroll
        for (int j = 0; j < 8; j++)
            a[j] += __shfl_xor(a[j], off);
    if (gp == 0) {                          // lanes 0..7 finalize + store 16B each
        float dv = dinv[i];
        short8 selfv = *(const short8*)&xb[(size_t)i * CIN + sl * 8];
        short8 o;
#pragma unroll
        for (int j = 0; j < 8; j++)
            o[j] = (short)f32_to_bf16((a[j] + bf16_to_f32((unsigned short)selfv[j])) * dv);
        *(short8*)&z[(size_t)i * CIN + sl * 8] = o;
    }
}

// ---------- fused GCN GEMMs: h = z*W1+b1 (K=64) -> LDS -> y = (h*W2)*dinv (K=128)
#define HPAD 136
__global__ __launch_bounds__(256) void gcn12_kernel(
        const unsigned short* __restrict__ Z, const unsigned short* __restrict__ W1T,
        const float* __restrict__ b1, const unsigned short* __restrict__ W2T,
        const float* __restrict__ dinv, unsigned short* __restrict__ Y) {
    __shared__ unsigned short hl[64][HPAD];
    int tid = threadIdx.x, wave = tid >> 6, lane = tid & 63, m = lane & 15, quad = lane >> 4;
    int row0 = blockIdx.x * 64 + wave * 16;
    int lrow0 = wave * 16;
    floatx4 acc[8] = {};
    for (int kc = 0; kc < CIN; kc += 32) {
        short8 af = *(const short8*)&Z[(size_t)(row0 + m) * CIN + kc + quad * 8];
#pragma unroll
        for (int t = 0; t < 8; t++) {
            short8 bf = *(const short8*)&W1T[(size_t)(t * 16 + m) * CIN + kc + quad * 8];
            acc[t] = __builtin_amdgcn_mfma_f32_16x16x32_bf16(af, bf, acc[t], 0, 0, 0);
        }
    }
#pragma unroll
    for (int t = 0; t < 8; t++) {
        int col = t * 16 + m;
        float bj = b1[col];
#pragma unroll
        for (int r = 0; r < 4; r++)
            hl[lrow0 + quad * 4 + r][col] = f32_to_bf16(acc[t][r] + bj);
    }
    asm volatile("s_waitcnt lgkmcnt(0)" ::: "memory");
    floatx4 acc2[8] = {};
    for (int kc = 0; kc < H; kc += 32) {
        short8 af = *(const short8*)&hl[lrow0 + m][kc + quad * 8];
#pragma unroll
        for (int t = 0; t < 8; t++) {
            short8 bf = *(const short8*)&W2T[(size_t)(t * 16 + m) * H + kc + quad * 8];
            acc2[t] = __builtin_amdgcn_mfma_f32_16x16x32_bf16(af, bf, acc2[t], 0, 0, 0);
        }
    }
    int rbase = row0 + quad * 4;
    float4 dv4 = *(const float4*)&dinv[rbase];
    float dv[4] = {dv4.x, dv4.y, dv4.z, dv4.w};
#pragma unroll
    for (int t = 0; t < 8; t++) {
        int col = t * 16 + m;
#pragma unroll
        for (int r = 0; r < 4; r++)
            Y[(size_t)(rbase + r) * H + col] = f32_to_bf16(acc2[t][r] * dv[r]);
    }
}

// ---------- layer-2 aggregation, vectorized gather: 16 lanes x short8 per row ----
__global__ void agg_kernel(const unsigned short* __restrict__ y,
                           const int* __restrict__ row_start, const int* __restrict__ cnt,
                           const int* __restrict__ csr_src, const float* __restrict__ dinv,
                           const float* __restrict__ bias, unsigned short* __restrict__ hout) {
    __shared__ float sred[16][8];
    int i = blockIdx.x;
    int t = threadIdx.x;                    // 128
    int sl = t & 15, gp = t >> 4;           // slice: 8 ch; groups 0-3 wave0, 4-7 wave1
    float a[8] = {0.f, 0.f, 0.f, 0.f, 0.f, 0.f, 0.f, 0.f};
    int rs = row_start[i], n = cnt[i];
    for (int p = gp; p < n; p += 8) {
        int s = csr_src[rs + p];            // broadcast within 16-lane slice group
        short8 v = *(const short8*)&y[(size_t)s * H + sl * 8];
#pragma unroll
        for (int j = 0; j < 8; j++)
            a[j] += bf16_to_f32((unsigned short)v[j]);
    }
#pragma unroll
    for (int off = 16; off < 64; off <<= 1)
#pragma unroll
        for (int j = 0; j < 8; j++)
            a[j] += __shfl_xor(a[j], off);
    if (t >= 64 && t < 80) {                // wave1 lanes 0..15: publish partials
#pragma unroll
        for (int j = 0; j < 8; j++) sred[sl][j] = a[j];
    }
    __syncthreads();
    if (t < 16) {                           // wave0 lanes 0..15 finalize + store
        float dv = dinv[i];
        short8 selfv = *(const short8*)&y[(size_t)i * H + sl * 8];
        short8 o;
#pragma unroll
        for (int j = 0; j < 8; j++) {
            float x = (a[j] + sred[sl][j] + bf16_to_f32((unsigned short)selfv[j])) * dv
                      + bias[sl * 8 + j];
            o[j] = (short)f32_to_bf16(x);
        }
        *(short8*)&hout[(size_t)i * H + sl * 8] = o;
    }
}

// ---------- QKV GEMM (N=384) with blocked epilogue ----------
__global__ __launch_bounds__(256) void mmqkv_kernel(const unsigned short* __restrict__ A,
        const unsigned short* __restrict__ B, const float* __restrict__ bias,
        unsigned short* __restrict__ Qx, unsigned short* __restrict__ Kx,
        unsigned short* __restrict__ Vtx) {
    __shared__ unsigned short vbuf[4][2][16][20];   // [wave][parity][hd][s(+pad)]
    int tid = threadIdx.x, wave = tid >> 6, lane = tid & 63, m = lane & 15, quad = lane >> 4;
    int row0 = blockIdx.x * 64 + wave * 16;
    floatx4 acc[24] = {};
    for (int kc = 0; kc < H; kc += 32) {
        short8 af = *(const short8*)&A[(size_t)(row0 + m) * H + kc + quad * 8];
#pragma unroll
        for (int t = 0; t < 24; t++) {
            short8 bf = *(const short8*)&B[(size_t)(t * 16 + m) * H + kc + quad * 8];
            acc[t] = __builtin_amdgcn_mfma_f32_16x16x32_bf16(af, bf, acc[t], 0, 0, 0);
        }
    }
    int rbase = row0 + quad * 4;                    // rows rbase..rbase+3, same batch
    int b = rbase >> 12, s0 = rbase & (S - 1);
    int s0t = row0 & (S - 1);                       // wave-tile base s (16 rows)
    int hdl = lane >> 2, sg = lane & 3;             // transposed-read mapping
#pragma unroll
    for (int t = 0; t < 24; t++) {
        int j = t * 16 + m;                         // 0..383
        float bj = bias[j];
        if (t < 8) {                                // Q (pre-scaled by log2e/sqrt(hd))
            int head = j >> 5, hd = j & 31;
            int bh = b * HEADS + head;
#pragma unroll
            for (int r = 0; r < 4; r++)
                Qx[((size_t)bh * S + s0 + r) * HD + hd] =
                    f32_to_bf16((acc[t][r] + bj) *
                                (0.17677669529663687f * 1.4426950408889634f));
        } else if (t < 16) {                        // K
            int jj = j & 127, head = jj >> 5, hd = jj & 31;
            int bh = b * HEADS + head;
#pragma unroll
            for (int r = 0; r < 4; r++)
                Kx[((size_t)bh * S + s0 + r) * HD + hd] = f32_to_bf16(acc[t][r] + bj);
        } else {                                    // V transposed via LDS
            int t2 = t - 16;                        // 0..7
            int head = t2 >> 1, hdb = (t2 & 1) * 16;
            int bh = b * HEADS + head;
            float v0 = acc[t][0] + bj, v1 = acc[t][1] + bj;
            float v2 = acc[t][2] + bj, v3 = acc[t][3] + bj;
            unsigned int d0, d1;
            asm("v_cvt_pk_bf16_f32 %0, %1, %2" : "=v"(d0) : "v"(v0), "v"(v1));
            asm("v_cvt_pk_bf16_f32 %0, %1, %2" : "=v"(d1) : "v"(v2), "v"(v3));
            uint2 wv; wv.x = d0; wv.y = d1;
            *(uint2*)&vbuf[wave][t2 & 1][m][quad * 4] = wv;
            asm volatile("s_waitcnt lgkmcnt(0)" ::: "memory");
            uint2 rv = *(const uint2*)&vbuf[wave][t2 & 1][hdl][sg * 4];
            *(uint2*)&Vtx[((size_t)bh * HD + hdb + hdl) * S + s0t + sg * 4] = rv;
        }
    }
}

// ---------- MFMA flash attention v7: 64 q-rows/wave, zero LDS, in-register P
// transpose, l on the MFMA pipe, XCD swizzle (2 bh-streams per XCD-L2).
// grid 256 (1 block/CU, 1 wave/SIMD), block 256.
// NOTE (R9): v_exp_f32 verified NOT issue-blocking (poly replacement raised
// VALU-busy time 51->74us) — keep the hardware transcendental.
__global__ __launch_bounds__(256) void attn7_kernel(
        const unsigned short* __restrict__ Qx, const unsigned short* __restrict__ Kx,
        const unsigned short* __restrict__ Vtx, unsigned short* __restrict__ Ob) {
    int tid = threadIdx.x, wave = tid >> 6, lane = tid & 63;
    int m = lane & 15, quad = lane >> 4;

    int n = blockIdx.x;                       // 0..255, XCD ~ n%8
    int id = (n & 7) * 32 + (n >> 3);         // XCD x owns ids [32x,32x+32) -> bh {2x,2x+1}
    int tile = id & 15, bh = id >> 4;

    const unsigned short* Qb  = Qx  + (size_t)bh * S * HD;
    const unsigned short* Kb  = Kx  + (size_t)bh * S * HD;
    const unsigned short* Vtb = Vtx + (size_t)bh * HD * S;

    int q0 = tile * 256 + wave * 64;
    short8 q[4];
#pragma unroll
    for (int t = 0; t < 4; t++)
        q[t] = *(const short8*)&Qb[(size_t)(q0 + t * 16 + m) * HD + quad * 8];

    floatx4 o0[4] = {}, o1[4] = {}, l[4] = {};

    short8 ones = {16256, 16256, 16256, 16256, 16256, 16256, 16256, 16256}; // bf16 1.0
    union PW { unsigned int u[4]; short8 s8; };

    // chunk 0 K/V
    short8 kf0 = *(const short8*)&Kb[(size_t)m * HD + quad * 8];
    short8 kf1 = *(const short8*)&Kb[(size_t)(m + 16) * HD + quad * 8];
    short8 vc0 = *(const short8*)&Vtb[(size_t)m * S + quad * 8];
    short8 vc1 = *(const short8*)&Vtb[(size_t)(m + 16) * S + quad * 8];

    for (int i = 0; i < S / 32; i++) {
        floatx4 z = {};
        // swapped QK^T for all 4 q-tiles (lane(m,quad): P^T[k=quad*4+r][q=m])
        floatx4 t0[4], t1[4];
#pragma unroll
        for (int t = 0; t < 4; t++) {
            t0[t] = __builtin_amdgcn_mfma_f32_16x16x32_bf16(kf0, q[t], z, 0, 0, 0);
            t1[t] = __builtin_amdgcn_mfma_f32_16x16x32_bf16(kf1, q[t], z, 0, 0, 0);
        }
        // K prefetch for chunk i+1 (used at top of next iter, ~full iter ahead)
        int ktn = ((i + 1) * 32) & (S - 1);
        kf0 = *(const short8*)&Kb[(size_t)(ktn + m) * HD + quad * 8];
        kf1 = *(const short8*)&Kb[(size_t)(ktn + m + 16) * HD + quad * 8];

        // exp2 -> pack bf16 -> in-register transpose, per tile
        PW pw[4];
#pragma unroll
        for (int t = 0; t < 4; t++) {
            float e0 = __builtin_amdgcn_exp2f(t0[t][0]);
            float e1 = __builtin_amdgcn_exp2f(t0[t][1]);
            float e2 = __builtin_amdgcn_exp2f(t0[t][2]);
            float e3 = __builtin_amdgcn_exp2f(t0[t][3]);
            float e4 = __builtin_amdgcn_exp2f(t1[t][0]);
            float e5 = __builtin_amdgcn_exp2f(t1[t][1]);
            float e6 = __builtin_amdgcn_exp2f(t1[t][2]);
            float e7 = __builtin_amdgcn_exp2f(t1[t][3]);
            unsigned int w0, w1, w2, w3;
            asm("v_cvt_pk_bf16_f32 %0, %1, %2" : "=v"(w0) : "v"(e0), "v"(e1));
            asm("v_cvt_pk_bf16_f32 %0, %1, %2" : "=v"(w1) : "v"(e2), "v"(e3));
            asm("v_cvt_pk_bf16_f32 %0, %1, %2" : "=v"(w2) : "v"(e4), "v"(e5));
            asm("v_cvt_pk_bf16_f32 %0, %1, %2" : "=v"(w3) : "v"(e6), "v"(e7));
            asm("v_permlane32_swap_b32 %0, %1" : "+v"(w0), "+v"(w2));
            asm("v_permlane32_swap_b32 %0, %1" : "+v"(w1), "+v"(w3));
            asm("v_permlane16_swap_b32 %0, %1" : "+v"(w0), "+v"(w2));
            asm("v_permlane16_swap_b32 %0, %1" : "+v"(w1), "+v"(w3));
            pw[t].u[0] = w0; pw[t].u[1] = w1; pw[t].u[2] = w2; pw[t].u[3] = w3;
        }

        // PV + row-sum l (MFMA pipe), then V prefetch for chunk i+1
#pragma unroll
        for (int t = 0; t < 4; t++) {
            o0[t] = __builtin_amdgcn_mfma_f32_16x16x32_bf16(pw[t].s8, vc0, o0[t], 0, 0, 0);
            o1[t] = __builtin_amdgcn_mfma_f32_16x16x32_bf16(pw[t].s8, vc1, o1[t], 0, 0, 0);
            l[t]  = __builtin_amdgcn_mfma_f32_16x16x32_bf16(pw[t].s8, ones, l[t], 0, 0, 0);
        }
        vc0 = *(const short8*)&Vtb[(size_t)m * S + ktn + quad * 8];
        vc1 = *(const short8*)&Vtb[(size_t)(m + 16) * S + ktn + quad * 8];
    }

    // epilogue: l is row-aligned with O (row = quad*4+r), no shuffles
    int batch = bh >> 2, head = bh & 3;
    int col = head * HD + m;
#pragma unroll
    for (int t = 0; t < 4; t++) {
        int grow = batch * S + q0 + t * 16 + quad * 4;
#pragma unroll
        for (int r = 0; r < 4; r++) {
            float inv = 1.f / l[t][r];
            Ob[(size_t)(grow + r) * H + col]      = f32_to_bf16(o0[t][r] * inv);
            Ob[(size_t)(grow + r) * H + col + 16] = f32_to_bf16(o1[t][r] * inv);
        }
    }
}

// ---------- output projection GEMM (N=128) + bias, dual-dtype store ----------
__global__ __launch_bounds__(256) void mmout_kernel(const unsigned short* __restrict__ A,
        const unsigned short* __restrict__ B, const float* __restrict__ bias,
        void* __restrict__ out, const int* __restrict__ flags) {
    int tid = threadIdx.x, wave = tid >> 6, lane = tid & 63, m = lane & 15, quad = lane >> 4;
    int row0 = blockIdx.x * 64 + wave * 16;
    floatx4 acc[8] = {};
    for (int kc = 0; kc < H; kc += 32) {
        short8 af = *(const short8*)&A[(size_t)(row0 + m) * H + kc + quad * 8];
#pragma unroll
        for (int t = 0; t < 8; t++) {
            short8 bf = *(const short8*)&B[(size_t)(t * 16 + m) * H + kc + quad * 8];
            acc[t] = __builtin_amdgcn_mfma_f32_16x16x32_bf16(af, bf, acc[t], 0, 0, 0);
        }
    }
    int rbase = row0 + quad * 4;
    int f32o = flags[0];
#pragma unroll
    for (int t = 0; t < 8; t++) {
        int col = t * 16 + m;
        float bj = bias[col];
#pragma unroll
        for (int r = 0; r < 4; r++) {
            float v = acc[t][r] + bj;
            if (f32o) ((float*)out)[(size_t)(rbase + r) * H + col] = v;
            else ((unsigned short*)out)[(size_t)(rbase + r) * H + col] = f32_to_bf16(v);
        }
    }
}

extern "C" void kernel_launch(void* const* d_in, const int* in_sizes, int n_in,
                              void* d_out, int out_size, void* d_ws, size_t ws_size,
                              hipStream_t stream) {
    const void* x_raw    = d_in[0];
    const int*  ei_raw   = (const int*)d_in[1];
    const void* W1_raw   = d_in[2];
    const void* b1_raw   = d_in[3];
    const void* W2_raw   = d_in[4];
    const void* b2_raw   = d_in[5];
    const void* Wq_raw   = d_in[6];
    const void* bq_raw   = d_in[7];
    const void* Wo_raw   = d_in[8];
    const void* bo_raw   = d_in[9];

    char* ws = (char*)d_ws;
    size_t o = 0;
    auto alloc = [&](size_t bytes) { void* p = ws + o; o += (bytes + 1023) & ~1023ull; return p; };

    int*   flags     = (int*)  alloc(1024);
    int*   cnt       = (int*)  alloc((size_t)GN * 4);
    int*   row_start = (int*)  alloc((size_t)GN * 4);
    float* dinv      = (float*)alloc((size_t)GN * 4);
    int*   csr_src   = (int*)  alloc((size_t)ETOT * 4);
    unsigned short* xb   = (unsigned short*)alloc((size_t)GN * CIN * 2);
    unsigned short* zb   = (unsigned short*)alloc((size_t)GN * CIN * 2);
    unsigned short* W1T  = (unsigned short*)alloc((size_t)H * CIN * 2);
    unsigned short* W2T  = (unsigned short*)alloc((size_t)H * H * 2);
    unsigned short* Wqb  = (unsigned short*)alloc((size_t)QKV * H * 2);
    unsigned short* Wob  = (unsigned short*)alloc((size_t)H * H * 2);
    float* b1f = (float*)alloc(H * 4);
    float* b2f = (float*)alloc(H * 4);
    float* bqf = (float*)alloc(QKV * 4);
    float* bof = (float*)alloc(H * 4);
    unsigned short* y_bf = (unsigned short*)alloc((size_t)GN * H * 2);
    unsigned short* h_bf = (unsigned short*)alloc((size_t)GN * H * 2);
    unsigned short* Qx   = (unsigned short*)alloc((size_t)16 * S * HD * 2);
    unsigned short* Kx   = (unsigned short*)alloc((size_t)16 * S * HD * 2);
    unsigned short* Vtx  = (unsigned short*)alloc((size_t)16 * S * HD * 2);
    unsigned short* Obf  = y_bf;   // y dead after agg

    detect_kernel<<<1, 256, 0, stream>>>((const unsigned short*)x_raw, ei_raw, flags);

    // CSR build: count+scan+dinv+fill in one dispatch (LDS atomics)
    csr_kernel<<<G, NPG, 0, stream>>>(ei_raw, flags, cnt, row_start, dinv, csr_src);

    // conversion (x pre-scaled by dinv for the reassociated layer 1)
    conv_all_kernel<<<(CTOT + 255) / 256, 256, 0, stream>>>(
        x_raw, W1_raw, b1_raw, W2_raw, b2_raw, Wq_raw, bq_raw, Wo_raw, bo_raw,
        xb, W1T, W2T, Wqb, Wob, b1f, b2f, bqf, bof, dinv, flags);

    // GCN layer 1 aggregate (vectorized), then fused GEMM1+GEMM2 (h in LDS)
    agg64_kernel<<<GN, 64, 0, stream>>>(xb, row_start, cnt, csr_src, dinv, zb);
    gcn12_kernel<<<GN / 64, 256, 0, stream>>>(zb, W1T, b1f, W2T, dinv, y_bf);
    // GCN layer 2 aggregate (vectorized) + bias
    agg_kernel<<<GN, 128, 0, stream>>>(y_bf, row_start, cnt, csr_src, dinv, b2f, h_bf);

    // attention
    mmqkv_kernel<<<GN / 64, 256, 0, stream>>>(h_bf, Wqb, bqf, Qx, Kx, Vtx);
    attn7_kernel<<<dim3(256), 256, 0, stream>>>(Qx, Kx, Vtx, Obf);
    mmout_kernel<<<GN / 64, 256, 0, stream>>>(Obf, Wob, bof, d_out, flags);
}